// Round 4
// baseline (620.918 us; speedup 1.0000x reference)
//
#include <hip/hip_runtime.h>

// EGNN forward — MFMA edge kernel, software-pipelined gathers, persistent blocks.
// ws (floats): h[N*64] | agg_m[N*64] | agg_x[N*3] | cnt[N] | WA[2048] | WB[2048] | bSum[64]
// d_out (floats): out[N*64] | coords_out[N*3]
// d_out doubles as bf16 gA/gB scratch between k_embed and k_edge.
//
// NOTE (round-3 bug): __shfl == ds_bpermute; reads from lanes inactive under
// the current exec mask are UNDEFINED. All index shfls are hoisted to
// non-divergent code (rIs[][]) before any `if (t < 3)`-style branch.

typedef __attribute__((ext_vector_type(4))) float f32x4;
typedef __attribute__((ext_vector_type(8))) short short8;

__device__ __forceinline__ void atomAddF(float* p, float v) { unsafeAtomicAdd(p, v); }

__device__ __forceinline__ unsigned short f2bf(float f) {
  unsigned int u = __builtin_bit_cast(unsigned int, f);
  unsigned int r = (u + 0x7FFFu + ((u >> 16) & 1u)) >> 16;
  return (unsigned short)r;
}
__device__ __forceinline__ float bf2f(unsigned short s) {
  unsigned int v = ((unsigned int)s) << 16;
  return __builtin_bit_cast(float, v);
}
__device__ __forceinline__ float lo_bf(unsigned int u) {
  return __builtin_bit_cast(float, u << 16);
}
__device__ __forceinline__ float hi_bf(unsigned int u) {
  return __builtin_bit_cast(float, u & 0xFFFF0000u);
}

// ---------------- k_fold ----------------
__global__ void k_fold(const float* __restrict__ W_in, const float* __restrict__ b_in,
                       const float* __restrict__ We1, const float* __restrict__ be1,
                       float* __restrict__ WA, float* __restrict__ WB,
                       float* __restrict__ bSum) {
  const int t = threadIdx.x;
  for (int idx = t; idx < 2048; idx += 256) {
    const int i = idx >> 6, n = idx & 63;
    float sa = 0.f, sb = 0.f;
    for (int h = 0; h < 64; ++h) {
      const float w = W_in[i * 64 + h];
      sa = fmaf(w, We1[h * 64 + n], sa);
      sb = fmaf(w, We1[(64 + h) * 64 + n], sb);
    }
    WA[idx] = sa;
    WB[idx] = sb;
  }
  if (t < 64) {
    float s = be1[t];
    for (int h = 0; h < 64; ++h)
      s = fmaf(b_in[h], We1[h * 64 + t] + We1[(64 + h) * 64 + t], s);
    bSum[t] = s;
  }
}

// ---------------- k_embed (+ agg zeroing) ----------------
__global__ __launch_bounds__(256) void k_embed(
    const float* __restrict__ nf, const float* __restrict__ W_in,
    const float* __restrict__ b_in, const float* __restrict__ WA,
    const float* __restrict__ WB, float* __restrict__ h,
    unsigned short* __restrict__ gA, unsigned short* __restrict__ gB,
    float* __restrict__ aggz, int N) {
  {
    const size_t tot = (size_t)N * 68;
    const size_t stride = (size_t)gridDim.x * 256;
    for (size_t i = (size_t)blockIdx.x * 256 + threadIdx.x; i * 4 < tot; i += stride) {
      const size_t b = i * 4;
      if (b + 4 <= tot)
        *reinterpret_cast<float4*>(aggz + b) = make_float4(0.f, 0.f, 0.f, 0.f);
      else
        for (size_t q = b; q < tot; ++q) aggz[q] = 0.f;
    }
  }
  __shared__ float Ws[3 * 2048];
  __shared__ float nfl[4][8][36];
  for (int i = threadIdx.x; i < 2048; i += 256) {
    Ws[i] = W_in[i];
    Ws[2048 + i] = WA[i];
    Ws[4096 + i] = WB[i];
  }
  __syncthreads();
  const int w = threadIdx.x >> 6, lane = threadIdx.x & 63;
  const float bv = b_in[lane];
  const int NG = (N + 7) >> 3;
  for (int ng = blockIdx.x * 4 + w; ng < NG; ng += gridDim.x * 4) {
    const int base = ng * 8;
    {
      const int nl = lane >> 3, ch = lane & 7;
      int n = base + nl;
      if (n >= N) n = N - 1;
      const f32x4 v = *reinterpret_cast<const f32x4*>(nf + (size_t)n * 32 + ch * 4);
      *reinterpret_cast<f32x4*>(&nfl[w][nl][ch * 4]) = v;
    }
    float ah[8], aa[8], ab[8];
#pragma unroll
    for (int i = 0; i < 8; ++i) { ah[i] = bv; aa[i] = 0.f; ab[i] = 0.f; }
    for (int k4 = 0; k4 < 8; ++k4) {
      float w0[3][4];
#pragma unroll
      for (int q = 0; q < 4; ++q) {
        w0[0][q] = Ws[(k4 * 4 + q) * 64 + lane];
        w0[1][q] = Ws[2048 + (k4 * 4 + q) * 64 + lane];
        w0[2][q] = Ws[4096 + (k4 * 4 + q) * 64 + lane];
      }
#pragma unroll
      for (int i = 0; i < 8; ++i) {
        const f32x4 x = *reinterpret_cast<const f32x4*>(&nfl[w][i][k4 * 4]);
#pragma unroll
        for (int q = 0; q < 4; ++q) {
          ah[i] = fmaf(x[q], w0[0][q], ah[i]);
          aa[i] = fmaf(x[q], w0[1][q], aa[i]);
          ab[i] = fmaf(x[q], w0[2][q], ab[i]);
        }
      }
    }
#pragma unroll
    for (int i = 0; i < 8; ++i) {
      const int n = base + i;
      if (n < N) {
        h[(size_t)n * 64 + lane] = ah[i];
        gA[(size_t)n * 64 + lane] = f2bf(aa[i]);
        gB[(size_t)n * 64 + lane] = f2bf(ab[i]);
      }
    }
  }
}

// ---------------- k_edge ----------------
struct EdgeLds {
  unsigned short We2t[64 * 72];
  unsigned short Wc1t[64 * 72];
  unsigned short Bea[64 * 40];
  unsigned short x[4][32 * 72];
  float cd[4][32 * 4];
};

__global__ __launch_bounds__(256, 3) void k_edge(
    const unsigned short* __restrict__ gA, const unsigned short* __restrict__ gB,
    const float* __restrict__ ea, const float* __restrict__ co,
    const int* __restrict__ eidx, const float* __restrict__ We1,
    const float* __restrict__ bSum, const float* __restrict__ be2,
    const float* __restrict__ We2, const float* __restrict__ bc1,
    const float* __restrict__ Wc1, const float* __restrict__ Wc2,
    const float* __restrict__ bc2, float* __restrict__ agg_m,
    float* __restrict__ agg_x, float* __restrict__ cnt, int E) {
  __shared__ EdgeLds S;
  const int tid = threadIdx.x;
  for (int i = tid; i < 4096; i += 256) {
    const int k = i >> 6, n = i & 63;
    S.We2t[n * 72 + k] = f2bf(We2[k * 64 + n]);
    S.Wc1t[n * 72 + k] = f2bf(Wc1[k * 64 + n]);
  }
  for (int i = tid; i < 2048; i += 256) {
    const int k = i >> 6, n = i & 63;
    const float v = (k < 16) ? We1[(129 + k) * 64 + n]
                             : ((k == 16) ? We1[128 * 64 + n] : 0.f);
    S.Bea[n * 40 + k] = f2bf(v);
  }
  __syncthreads();

  const int w = tid >> 6, lane = tid & 63;
  const int g = lane >> 4, t = lane & 15;
  const float bc2v = bc2[0];

  float bS_r[4], be2_r[4], bc1_r[4], wc2_r[4];
#pragma unroll
  for (int nt = 0; nt < 4; ++nt) {
    const int n = t + 16 * nt;
    bS_r[nt] = bSum[n];
    be2_r[nt] = be2[n];
    bc1_r[nt] = bc1[n];
    wc2_r[nt] = Wc2[n];
  }

  unsigned short* xw = &S.x[w][0];
  float* cdw = &S.cd[w][0];
  const long ngroups = ((long)E + 31) >> 5;
  const long GS = (long)gridDim.x * 4;

  int cur_idx = 0, pf_idx = 0, nxt_saved = 0;
  uint4 sA[4], sB[4];
  f32x4 eav[2][2];

  auto load_idx = [&](long gI) -> int {
    long e = gI * 32 + (lane & 31);
    if (e >= E) e = E - 1;
    if (e < 0) e = 0;
    const size_t off = (lane < 32) ? 0 : (size_t)E;
    return eidx[off + (size_t)e];
  };

  long grp = (long)blockIdx.x * 4 + w;
  if (grp < ngroups) {
    cur_idx = load_idx(grp);
#pragma unroll
    for (int rr = 0; rr < 4; ++rr) {
      const int el = rr * 8 + (lane >> 3), ch = lane & 7;
      const int rI = __shfl(cur_idx, el, 64);
      const int cI = __shfl(cur_idx, el + 32, 64);
      sA[rr] = *reinterpret_cast<const uint4*>(gA + (size_t)rI * 64 + ch * 8);
      sB[rr] = *reinterpret_cast<const uint4*>(gB + (size_t)cI * 64 + ch * 8);
    }
#pragma unroll
    for (int mt = 0; mt < 2; ++mt) {
      long eg = grp * 32 + t + 16 * mt;
      if (eg >= E) eg = E - 1;
      const float* pe = ea + (size_t)eg * 16 + (g & 1) * 8;
      eav[mt][0] = *reinterpret_cast<const f32x4*>(pe);
      eav[mt][1] = *reinterpret_cast<const f32x4*>(pe + 4);
    }
    pf_idx = load_idx(grp + GS);
  }

  for (; grp < ngroups; grp += GS) {
    const long e0 = grp * 32;
    const int el0 = lane & 31;
    const int rE = __shfl(cur_idx, el0, 64);
    const int cE = __shfl(cur_idx, el0 + 32, 64);
    const float rx = co[(size_t)rE * 3 + 0], ry = co[(size_t)rE * 3 + 1],
                rz = co[(size_t)rE * 3 + 2];
    const float cx = co[(size_t)cE * 3 + 0], cy = co[(size_t)cE * 3 + 1],
                cz = co[(size_t)cE * 3 + 2];
#pragma unroll
    for (int rr = 0; rr < 4; ++rr) {
      const int el = rr * 8 + (lane >> 3), ch = lane & 7;
      const unsigned int a[4] = {sA[rr].x, sA[rr].y, sA[rr].z, sA[rr].w};
      const unsigned int b[4] = {sB[rr].x, sB[rr].y, sB[rr].z, sB[rr].w};
      uint4 o;
      unsigned int r[4];
#pragma unroll
      for (int q = 0; q < 4; ++q) {
        const float s0 = lo_bf(a[q]) + lo_bf(b[q]);
        const float s1 = hi_bf(a[q]) + hi_bf(b[q]);
        r[q] = ((unsigned int)f2bf(s1) << 16) | (unsigned int)f2bf(s0);
      }
      o.x = r[0]; o.y = r[1]; o.z = r[2]; o.w = r[3];
      *reinterpret_cast<uint4*>(&xw[el * 72 + ch * 8]) = o;
    }
    if (lane < 32) {
      const float dx = rx - cx, dy = ry - cy, dz = rz - cz;
      f32x4 c4;
      c4[0] = dx; c4[1] = dy; c4[2] = dz; c4[3] = dx * dx + dy * dy + dz * dz;
      *reinterpret_cast<f32x4*>(&cdw[el0 * 4]) = c4;
    }
    // hoisted, non-divergent index redistribution for ALL atomic sites
    int rIs[2][4];
#pragma unroll
    for (int mt = 0; mt < 2; ++mt)
#pragma unroll
      for (int j = 0; j < 4; ++j)
        rIs[mt][j] = __shfl(cur_idx, g * 4 + j + 16 * mt, 64);

    short8 a1[2];
#pragma unroll
    for (int mt = 0; mt < 2; ++mt) {
      short8 a = {};
      if (g < 2) {
#pragma unroll
        for (int q = 0; q < 4; ++q) {
          a[q] = (short)f2bf(eav[mt][0][q]);
          a[4 + q] = (short)f2bf(eav[mt][1][q]);
        }
      } else if (g == 2) {
        a[0] = (short)f2bf(cdw[(t + 16 * mt) * 4 + 3]);
      }
      a1[mt] = a;
    }
    {
      const int n_idx = pf_idx;
#pragma unroll
      for (int rr = 0; rr < 4; ++rr) {
        const int el = rr * 8 + (lane >> 3), ch = lane & 7;
        const int rI = __shfl(n_idx, el, 64);
        const int cI = __shfl(n_idx, el + 32, 64);
        sA[rr] = *reinterpret_cast<const uint4*>(gA + (size_t)rI * 64 + ch * 8);
        sB[rr] = *reinterpret_cast<const uint4*>(gB + (size_t)cI * 64 + ch * 8);
      }
#pragma unroll
      for (int mt = 0; mt < 2; ++mt) {
        long eg = (grp + GS) * 32 + t + 16 * mt;
        if (eg >= E) eg = E - 1;
        const float* pe = ea + (size_t)eg * 16 + (g & 1) * 8;
        eav[mt][0] = *reinterpret_cast<const f32x4*>(pe);
        eav[mt][1] = *reinterpret_cast<const f32x4*>(pe + 4);
      }
      pf_idx = load_idx(grp + 2 * GS);
      nxt_saved = n_idx;
    }
    f32x4 acc[2][4];
#pragma unroll
    for (int mt = 0; mt < 2; ++mt)
#pragma unroll
      for (int nt = 0; nt < 4; ++nt)
#pragma unroll
        for (int j = 0; j < 4; ++j) {
          const int row = g * 4 + j + 16 * mt, col = t + 16 * nt;
          acc[mt][nt][j] = bf2f(xw[row * 72 + col]) + bS_r[nt];
        }
#pragma unroll
    for (int mt = 0; mt < 2; ++mt)
#pragma unroll
      for (int nt = 0; nt < 4; ++nt) {
        const short8 b = *reinterpret_cast<const short8*>(&S.Bea[(t + 16 * nt) * 40 + g * 8]);
        acc[mt][nt] = __builtin_amdgcn_mfma_f32_16x16x32_bf16(a1[mt], b, acc[mt][nt], 0, 0, 0);
      }
#pragma unroll
    for (int mt = 0; mt < 2; ++mt)
#pragma unroll
      for (int nt = 0; nt < 4; ++nt)
#pragma unroll
        for (int j = 0; j < 4; ++j) {
          const float v = fmaxf(acc[mt][nt][j], 0.f);
          xw[(g * 4 + j + 16 * mt) * 72 + t + 16 * nt] = f2bf(v);
        }
    short8 A2[2][2];
#pragma unroll
    for (int mt = 0; mt < 2; ++mt)
#pragma unroll
      for (int kt = 0; kt < 2; ++kt)
        A2[mt][kt] = *reinterpret_cast<const short8*>(&xw[(t + 16 * mt) * 72 + kt * 32 + g * 8]);
    f32x4 m2[2][4];
#pragma unroll
    for (int mt = 0; mt < 2; ++mt)
#pragma unroll
      for (int nt = 0; nt < 4; ++nt) {
        f32x4 c;
        c[0] = be2_r[nt]; c[1] = be2_r[nt]; c[2] = be2_r[nt]; c[3] = be2_r[nt];
#pragma unroll
        for (int kt = 0; kt < 2; ++kt) {
          const short8 b = *reinterpret_cast<const short8*>(
              &S.We2t[(t + 16 * nt) * 72 + kt * 32 + g * 8]);
          c = __builtin_amdgcn_mfma_f32_16x16x32_bf16(A2[mt][kt], b, c, 0, 0, 0);
        }
#pragma unroll
        for (int j = 0; j < 4; ++j) c[j] = fmaxf(c[j], 0.f);
        m2[mt][nt] = c;
      }
#pragma unroll
    for (int mt = 0; mt < 2; ++mt)
#pragma unroll
      for (int nt = 0; nt < 4; ++nt)
#pragma unroll
        for (int j = 0; j < 4; ++j)
          xw[(g * 4 + j + 16 * mt) * 72 + t + 16 * nt] = f2bf(m2[mt][nt][j]);
#pragma unroll
    for (int mt = 0; mt < 2; ++mt)
#pragma unroll
      for (int j = 0; j < 4; ++j) {
        const int row = g * 4 + j + 16 * mt;
        const int rI = rIs[mt][j];
        if (e0 + row < E) {
          float* base = agg_m + (size_t)rI * 64 + t;
#pragma unroll
          for (int nt = 0; nt < 4; ++nt) atomAddF(base + 16 * nt, m2[mt][nt][j]);
        }
      }
    short8 A3[2][2];
#pragma unroll
    for (int mt = 0; mt < 2; ++mt)
#pragma unroll
      for (int kt = 0; kt < 2; ++kt)
        A3[mt][kt] = *reinterpret_cast<const short8*>(&xw[(t + 16 * mt) * 72 + kt * 32 + g * 8]);
    f32x4 p[2][4];
#pragma unroll
    for (int mt = 0; mt < 2; ++mt)
#pragma unroll
      for (int nt = 0; nt < 4; ++nt) {
        f32x4 c;
        c[0] = bc1_r[nt]; c[1] = bc1_r[nt]; c[2] = bc1_r[nt]; c[3] = bc1_r[nt];
#pragma unroll
        for (int kt = 0; kt < 2; ++kt) {
          const short8 b = *reinterpret_cast<const short8*>(
              &S.Wc1t[(t + 16 * nt) * 72 + kt * 32 + g * 8]);
          c = __builtin_amdgcn_mfma_f32_16x16x32_bf16(A3[mt][kt], b, c, 0, 0, 0);
        }
#pragma unroll
        for (int j = 0; j < 4; ++j) c[j] = fmaxf(c[j], 0.f);
        p[mt][nt] = c;
      }
    float sv[2][4];
#pragma unroll
    for (int mt = 0; mt < 2; ++mt)
#pragma unroll
      for (int j = 0; j < 4; ++j) {
        float ps = 0.f;
#pragma unroll
        for (int nt = 0; nt < 4; ++nt) ps = fmaf(p[mt][nt][j], wc2_r[nt], ps);
        sv[mt][j] = ps;
      }
#pragma unroll
    for (int d = 1; d < 16; d <<= 1)
#pragma unroll
      for (int mt = 0; mt < 2; ++mt)
#pragma unroll
        for (int j = 0; j < 4; ++j) sv[mt][j] += __shfl_xor(sv[mt][j], d, 64);
#pragma unroll
    for (int mt = 0; mt < 2; ++mt)
#pragma unroll
      for (int j = 0; j < 4; ++j) sv[mt][j] += bc2v;
    if (t < 3) {
#pragma unroll
      for (int mt = 0; mt < 2; ++mt)
#pragma unroll
        for (int j = 0; j < 4; ++j) {
          const int row = g * 4 + j + 16 * mt;
          if (e0 + row < E)
            atomAddF(agg_x + (size_t)rIs[mt][j] * 3 + t, cdw[row * 4 + t] * sv[mt][j]);
        }
    } else if (t == 3) {
#pragma unroll
      for (int mt = 0; mt < 2; ++mt)
#pragma unroll
        for (int j = 0; j < 4; ++j) {
          const int row = g * 4 + j + 16 * mt;
          if (e0 + row < E) atomAddF(cnt + rIs[mt][j], 1.0f);
        }
    }
    cur_idx = nxt_saved;
  }
}

// ---------------- k_node ----------------
__global__ __launch_bounds__(256) void k_node(
    const float* __restrict__ h, const float* __restrict__ agg_m,
    const float* __restrict__ agg_x, const float* __restrict__ cnt,
    const float* __restrict__ co,
    const float* __restrict__ Wn1, const float* __restrict__ bn1,
    const float* __restrict__ Wn2, const float* __restrict__ bn2,
    const float* __restrict__ Wo, const float* __restrict__ bo,
    float* __restrict__ out, float* __restrict__ co_out, int N) {
  __shared__ float Wn1s[128 * 64];
  __shared__ float Wn2s[64 * 64];
  __shared__ float Wos[64 * 64];
  __shared__ float bn1s[64], bn2s[64], bos[64];
  __shared__ float xls[4][136];

  for (int i = threadIdx.x; i < 128 * 64; i += 256) Wn1s[i] = Wn1[i];
  for (int i = threadIdx.x; i < 64 * 64; i += 256) {
    Wn2s[i] = Wn2[i];
    Wos[i] = Wo[i];
  }
  if (threadIdx.x < 64) {
    bn1s[threadIdx.x] = bn1[threadIdx.x];
    bn2s[threadIdx.x] = bn2[threadIdx.x];
    bos[threadIdx.x] = bo[threadIdx.x];
  }
  __syncthreads();

  const int wave = threadIdx.x >> 6, lane = threadIdx.x & 63;
  float* xw = xls[wave];
  const int nwaves = gridDim.x * 4;

  for (int n = blockIdx.x * 4 + wave; n < N; n += nwaves) {
    xw[lane] = h[(size_t)n * 64 + lane];
    xw[64 + lane] = agg_m[(size_t)n * 64 + lane];

    float a = bn1s[lane];
    for (int kk = 0; kk < 32; ++kk) {
      const float4 xv = *reinterpret_cast<const float4*>(&xw[kk * 4]);
      a = fmaf(xv.x, Wn1s[(kk * 4 + 0) * 64 + lane], a);
      a = fmaf(xv.y, Wn1s[(kk * 4 + 1) * 64 + lane], a);
      a = fmaf(xv.z, Wn1s[(kk * 4 + 2) * 64 + lane], a);
      a = fmaf(xv.w, Wn1s[(kk * 4 + 3) * 64 + lane], a);
    }
    a = fmaxf(a, 0.0f);
    xw[lane] = a;

    float a2 = bn2s[lane];
    for (int kk = 0; kk < 16; ++kk) {
      const float4 xv = *reinterpret_cast<const float4*>(&xw[kk * 4]);
      a2 = fmaf(xv.x, Wn2s[(kk * 4 + 0) * 64 + lane], a2);
      a2 = fmaf(xv.y, Wn2s[(kk * 4 + 1) * 64 + lane], a2);
      a2 = fmaf(xv.z, Wn2s[(kk * 4 + 2) * 64 + lane], a2);
      a2 = fmaf(xv.w, Wn2s[(kk * 4 + 3) * 64 + lane], a2);
    }
    xw[64 + lane] = a2;

    float a3 = bos[lane];
    for (int kk = 0; kk < 16; ++kk) {
      const float4 xv = *reinterpret_cast<const float4*>(&xw[64 + kk * 4]);
      a3 = fmaf(xv.x, Wos[(kk * 4 + 0) * 64 + lane], a3);
      a3 = fmaf(xv.y, Wos[(kk * 4 + 1) * 64 + lane], a3);
      a3 = fmaf(xv.z, Wos[(kk * 4 + 2) * 64 + lane], a3);
      a3 = fmaf(xv.w, Wos[(kk * 4 + 3) * 64 + lane], a3);
    }
    out[(size_t)n * 64 + lane] = a3;

    if (lane < 3)
      co_out[(size_t)n * 3 + lane] =
          co[(size_t)n * 3 + lane] + agg_x[(size_t)n * 3 + lane] / fmaxf(cnt[n], 1.0f);
  }
}

extern "C" void kernel_launch(void* const* d_in, const int* in_sizes, int n_in,
                              void* d_out, int out_size, void* d_ws, size_t ws_size,
                              hipStream_t stream) {
  const float* nf = (const float*)d_in[0];
  const float* ea = (const float*)d_in[1];
  const float* co = (const float*)d_in[2];
  const int* ei = (const int*)d_in[3];
  const float* W_in = (const float*)d_in[4];
  const float* b_in = (const float*)d_in[5];
  const float* W_out = (const float*)d_in[6];
  const float* b_out = (const float*)d_in[7];
  const float* We1 = (const float*)d_in[8];
  const float* be1 = (const float*)d_in[9];
  const float* We2 = (const float*)d_in[10];
  const float* be2 = (const float*)d_in[11];
  const float* Wn1 = (const float*)d_in[12];
  const float* bn1 = (const float*)d_in[13];
  const float* Wn2 = (const float*)d_in[14];
  const float* bn2 = (const float*)d_in[15];
  const float* Wc1 = (const float*)d_in[16];
  const float* bc1 = (const float*)d_in[17];
  const float* Wc2 = (const float*)d_in[18];
  const float* bc2 = (const float*)d_in[19];

  const int N = in_sizes[0] / 32;
  const int E = in_sizes[1] / 16;

  float* ws = (float*)d_ws;
  float* h = ws;
  float* agg_m = ws + (size_t)N * 64;
  float* agg_x = agg_m + (size_t)N * 64;
  float* cntb = agg_x + (size_t)N * 3;
  float* WA = cntb + N;
  float* WB = WA + 2048;
  float* bSum = WB + 2048;

  float* outp = (float*)d_out;
  float* co_out = outp + (size_t)N * 64;
  unsigned short* gA = (unsigned short*)d_out;
  unsigned short* gB = gA + (size_t)N * 64;

  k_fold<<<1, 256, 0, stream>>>(W_in, b_in, We1, be1, WA, WB, bSum);
  k_embed<<<2048, 256, 0, stream>>>(nf, W_in, b_in, WA, WB, h, gA, gB, agg_m, N);
  k_edge<<<768, 256, 0, stream>>>(gA, gB, ea, co, ei, We1, bSum, be2, We2,
                                  bc1, Wc1, Wc2, bc2, agg_m, agg_x, cntb, E);
  k_node<<<2048, 256, 0, stream>>>(h, agg_m, agg_x, cntb, co, Wn1, bn1, Wn2,
                                   bn2, W_out, b_out, outp, co_out, N);
}

// Round 5
// 515.946 us; speedup vs baseline: 1.2035x; 1.2035x over previous
//
#include <hip/hip_runtime.h>

// EGNN forward — counting-sort edges by row, MFMA edge MLP, run-compressed
// atomic aggregation.
// ws (words): h[N*64] | agg_m[N*64] | agg_x[N*3] | deg[N](int) | WA[2048] |
//             WB[2048] | bSum[64] | rowStart[N](int) | rowNext[N](int) |
//             perm[E](int) | rowS[E](int) | colS[E](int) | bsumBuf[512](int)
// d_out (floats): out[N*64] | coords_out[N*3]; doubles as bf16 gA/gB scratch.

typedef __attribute__((ext_vector_type(4))) float f32x4;
typedef __attribute__((ext_vector_type(8))) short short8;

__device__ __forceinline__ void atomAddF(float* p, float v) { unsafeAtomicAdd(p, v); }

__device__ __forceinline__ unsigned short f2bf(float f) {
  unsigned int u = __builtin_bit_cast(unsigned int, f);
  unsigned int r = (u + 0x7FFFu + ((u >> 16) & 1u)) >> 16;
  return (unsigned short)r;
}
__device__ __forceinline__ float bf2f(unsigned short s) {
  unsigned int v = ((unsigned int)s) << 16;
  return __builtin_bit_cast(float, v);
}
__device__ __forceinline__ float lo_bf(unsigned int u) {
  return __builtin_bit_cast(float, u << 16);
}
__device__ __forceinline__ float hi_bf(unsigned int u) {
  return __builtin_bit_cast(float, u & 0xFFFF0000u);
}

// ---------------- k_fold ----------------
__global__ void k_fold(const float* __restrict__ W_in, const float* __restrict__ b_in,
                       const float* __restrict__ We1, const float* __restrict__ be1,
                       float* __restrict__ WA, float* __restrict__ WB,
                       float* __restrict__ bSum) {
  const int t = threadIdx.x;
  for (int idx = t; idx < 2048; idx += 256) {
    const int i = idx >> 6, n = idx & 63;
    float sa = 0.f, sb = 0.f;
    for (int h = 0; h < 64; ++h) {
      const float w = W_in[i * 64 + h];
      sa = fmaf(w, We1[h * 64 + n], sa);
      sb = fmaf(w, We1[(64 + h) * 64 + n], sb);
    }
    WA[idx] = sa;
    WB[idx] = sb;
  }
  if (t < 64) {
    float s = be1[t];
    for (int h = 0; h < 64; ++h)
      s = fmaf(b_in[h], We1[h * 64 + t] + We1[(64 + h) * 64 + t], s);
    bSum[t] = s;
  }
}

// ---------------- k_embed (+ zero agg_m|agg_x|deg) ----------------
__global__ __launch_bounds__(256) void k_embed(
    const float* __restrict__ nf, const float* __restrict__ W_in,
    const float* __restrict__ b_in, const float* __restrict__ WA,
    const float* __restrict__ WB, float* __restrict__ h,
    unsigned short* __restrict__ gA, unsigned short* __restrict__ gB,
    float* __restrict__ aggz, int N) {
  {
    const size_t tot = (size_t)N * 68;  // agg_m(64) + agg_x(3) + deg(1)
    const size_t stride = (size_t)gridDim.x * 256;
    for (size_t i = (size_t)blockIdx.x * 256 + threadIdx.x; i * 4 < tot; i += stride) {
      const size_t b = i * 4;
      if (b + 4 <= tot)
        *reinterpret_cast<float4*>(aggz + b) = make_float4(0.f, 0.f, 0.f, 0.f);
      else
        for (size_t q = b; q < tot; ++q) aggz[q] = 0.f;
    }
  }
  __shared__ float Ws[3 * 2048];
  __shared__ float nfl[4][8][36];
  for (int i = threadIdx.x; i < 2048; i += 256) {
    Ws[i] = W_in[i];
    Ws[2048 + i] = WA[i];
    Ws[4096 + i] = WB[i];
  }
  __syncthreads();
  const int w = threadIdx.x >> 6, lane = threadIdx.x & 63;
  const float bv = b_in[lane];
  const int NG = (N + 7) >> 3;
  for (int ng = blockIdx.x * 4 + w; ng < NG; ng += gridDim.x * 4) {
    const int base = ng * 8;
    {
      const int nl = lane >> 3, ch = lane & 7;
      int n = base + nl;
      if (n >= N) n = N - 1;
      const f32x4 v = *reinterpret_cast<const f32x4*>(nf + (size_t)n * 32 + ch * 4);
      *reinterpret_cast<f32x4*>(&nfl[w][nl][ch * 4]) = v;
    }
    float ah[8], aa[8], ab[8];
#pragma unroll
    for (int i = 0; i < 8; ++i) { ah[i] = bv; aa[i] = 0.f; ab[i] = 0.f; }
    for (int k4 = 0; k4 < 8; ++k4) {
      float w0[3][4];
#pragma unroll
      for (int q = 0; q < 4; ++q) {
        w0[0][q] = Ws[(k4 * 4 + q) * 64 + lane];
        w0[1][q] = Ws[2048 + (k4 * 4 + q) * 64 + lane];
        w0[2][q] = Ws[4096 + (k4 * 4 + q) * 64 + lane];
      }
#pragma unroll
      for (int i = 0; i < 8; ++i) {
        const f32x4 x = *reinterpret_cast<const f32x4*>(&nfl[w][i][k4 * 4]);
#pragma unroll
        for (int q = 0; q < 4; ++q) {
          ah[i] = fmaf(x[q], w0[0][q], ah[i]);
          aa[i] = fmaf(x[q], w0[1][q], aa[i]);
          ab[i] = fmaf(x[q], w0[2][q], ab[i]);
        }
      }
    }
#pragma unroll
    for (int i = 0; i < 8; ++i) {
      const int n = base + i;
      if (n < N) {
        h[(size_t)n * 64 + lane] = ah[i];
        gA[(size_t)n * 64 + lane] = f2bf(aa[i]);
        gB[(size_t)n * 64 + lane] = f2bf(ab[i]);
      }
    }
  }
}

// ---------------- sort: histogram / scan / scatter ----------------
__global__ __launch_bounds__(256) void k_hist(const int* __restrict__ eidx,
                                              int* __restrict__ deg, int E) {
  for (int e = blockIdx.x * 256 + threadIdx.x; e < E; e += gridDim.x * 256)
    atomicAdd(&deg[eidx[e]], 1);
}

__global__ __launch_bounds__(256) void k_scanA(const int* __restrict__ deg,
                                               int* __restrict__ excl,
                                               int* __restrict__ bsum, int N) {
  __shared__ int s[256];
  const int t = threadIdx.x;
  const int i = blockIdx.x * 256 + t;
  const int v = (i < N) ? deg[i] : 0;
  s[t] = v;
  __syncthreads();
#pragma unroll
  for (int off = 1; off < 256; off <<= 1) {
    int x = 0;
    if (t >= off) x = s[t - off];
    __syncthreads();
    s[t] += x;
    __syncthreads();
  }
  if (i < N) excl[i] = s[t] - v;
  if (t == 255) bsum[blockIdx.x] = s[255];
}

__global__ __launch_bounds__(512) void k_scanB(int* __restrict__ bsum, int nb) {
  __shared__ int s[512];
  const int t = threadIdx.x;
  s[t] = (t < nb) ? bsum[t] : 0;
  __syncthreads();
  if (t == 0) {
    int run = 0;
    for (int i = 0; i < nb; ++i) {
      const int v = s[i];
      s[i] = run;
      run += v;
    }
  }
  __syncthreads();
  if (t < nb) bsum[t] = s[t];
}

__global__ __launch_bounds__(256) void k_scanC(int* __restrict__ excl,
                                               const int* __restrict__ bsum,
                                               int* __restrict__ rowNext, int N) {
  const int i = blockIdx.x * 256 + threadIdx.x;
  if (i < N) {
    const int v = excl[i] + bsum[i >> 8];
    excl[i] = v;
    rowNext[i] = v;
  }
}

__global__ __launch_bounds__(256) void k_scatter(const int* __restrict__ eidx,
                                                 int* __restrict__ rowNext,
                                                 int* __restrict__ perm,
                                                 int* __restrict__ rowS,
                                                 int* __restrict__ colS, int E) {
  for (int e = blockIdx.x * 256 + threadIdx.x; e < E; e += gridDim.x * 256) {
    const int r = eidx[e];
    const int c = eidx[E + e];
    const int pos = atomicAdd(&rowNext[r], 1);
    perm[pos] = e;
    rowS[pos] = r;
    colS[pos] = c;
  }
}

// ---------------- k_edge (sorted, run-compressed aggregation) ------------
struct EdgeLds {
  unsigned short We2t[64 * 72];
  unsigned short Wc1t[64 * 72];
  unsigned short Bea[64 * 40];
  unsigned short x[4][32 * 72];  // staged sum -> t1 -> m (bf16)
  float cd[4][32 * 4];           // dx,dy,dz,(radial -> s)
  int idx[4][32];                // sorted row ids
};

__global__ __launch_bounds__(256, 3) void k_edge(
    const unsigned short* __restrict__ gA, const unsigned short* __restrict__ gB,
    const float* __restrict__ ea, const float* __restrict__ co,
    const int* __restrict__ perm, const int* __restrict__ rowS,
    const int* __restrict__ colS, const float* __restrict__ We1,
    const float* __restrict__ bSum, const float* __restrict__ be2,
    const float* __restrict__ We2, const float* __restrict__ bc1,
    const float* __restrict__ Wc1, const float* __restrict__ Wc2,
    const float* __restrict__ bc2, float* __restrict__ agg_m,
    float* __restrict__ agg_x, int E) {
  __shared__ EdgeLds S;
  const int tid = threadIdx.x;
  for (int i = tid; i < 4096; i += 256) {
    const int k = i >> 6, n = i & 63;
    S.We2t[n * 72 + k] = f2bf(We2[k * 64 + n]);
    S.Wc1t[n * 72 + k] = f2bf(Wc1[k * 64 + n]);
  }
  for (int i = tid; i < 2048; i += 256) {
    const int k = i >> 6, n = i & 63;
    const float v = (k < 16) ? We1[(129 + k) * 64 + n]
                             : ((k == 16) ? We1[128 * 64 + n] : 0.f);
    S.Bea[n * 40 + k] = f2bf(v);
  }
  __syncthreads();

  const int w = tid >> 6, lane = tid & 63;
  const int g = lane >> 4, t = lane & 15;
  const float bc2v = bc2[0];

  float bS_r[4], be2_r[4], bc1_r[4], wc2_r[4];
#pragma unroll
  for (int nt = 0; nt < 4; ++nt) {
    const int n = t + 16 * nt;
    bS_r[nt] = bSum[n];
    be2_r[nt] = be2[n];
    bc1_r[nt] = bc1[n];
    wc2_r[nt] = Wc2[n];
  }

  unsigned short* xw = &S.x[w][0];
  float* cdw = &S.cd[w][0];
  int* idxw = &S.idx[w][0];
  const int ngroups = (E + 31) >> 5;

  for (int grp = blockIdx.x * 4 + w; grp < ngroups; grp += gridDim.x * 4) {
    const int e0 = grp * 32;
    int e = e0 + (lane & 31);
    if (e >= E) e = E - 1;
    const int rc = (lane < 32) ? rowS[e] : colS[e];
    const int pe_ = perm[e];
    if (lane < 32) idxw[lane] = rc;

    // --- coord loads (rows localized by sort; cols random) ---
    const int el0 = lane & 31;
    const int rE = __shfl(rc, el0, 64);
    const int cE = __shfl(rc, el0 + 32, 64);
    const float rx = co[(size_t)rE * 3 + 0], ry = co[(size_t)rE * 3 + 1],
                rz = co[(size_t)rE * 3 + 2];
    const float cx = co[(size_t)cE * 3 + 0], cy = co[(size_t)cE * 3 + 1],
                cz = co[(size_t)cE * 3 + 2];

    // --- gA[row]+gB[col] staged sum -> x tile ---
#pragma unroll
    for (int rr = 0; rr < 4; ++rr) {
      const int el = rr * 8 + (lane >> 3), ch = lane & 7;
      const int rI = __shfl(rc, el, 64);
      const int cI = __shfl(rc, el + 32, 64);
      const uint4 va = *reinterpret_cast<const uint4*>(gA + (size_t)rI * 64 + ch * 8);
      const uint4 vb = *reinterpret_cast<const uint4*>(gB + (size_t)cI * 64 + ch * 8);
      const unsigned int a[4] = {va.x, va.y, va.z, va.w};
      const unsigned int b[4] = {vb.x, vb.y, vb.z, vb.w};
      uint4 o;
      unsigned int r[4];
#pragma unroll
      for (int q = 0; q < 4; ++q) {
        const float s0 = lo_bf(a[q]) + lo_bf(b[q]);
        const float s1 = hi_bf(a[q]) + hi_bf(b[q]);
        r[q] = ((unsigned int)f2bf(s1) << 16) | (unsigned int)f2bf(s0);
      }
      o.x = r[0]; o.y = r[1]; o.z = r[2]; o.w = r[3];
      *reinterpret_cast<uint4*>(&xw[el * 72 + ch * 8]) = o;
    }
    if (lane < 32) {
      const float dx = rx - cx, dy = ry - cy, dz = rz - cz;
      f32x4 c4;
      c4[0] = dx; c4[1] = dy; c4[2] = dz; c4[3] = dx * dx + dy * dy + dz * dz;
      *reinterpret_cast<f32x4*>(&cdw[el0 * 4]) = c4;
    }

    // --- layer-1 A fragments: ea (via perm) + radial ---
    short8 a1[2];
#pragma unroll
    for (int mt = 0; mt < 2; ++mt) {
      const int eaI = __shfl(pe_, t + 16 * mt, 64);
      short8 a = {};
      if (g < 2) {
        const float* pe2 = ea + (size_t)eaI * 16 + (g & 1) * 8;
        const f32x4 x0 = *reinterpret_cast<const f32x4*>(pe2);
        const f32x4 x1 = *reinterpret_cast<const f32x4*>(pe2 + 4);
#pragma unroll
        for (int q = 0; q < 4; ++q) {
          a[q] = (short)f2bf(x0[q]);
          a[4 + q] = (short)f2bf(x1[q]);
        }
      } else if (g == 2) {
        a[0] = (short)f2bf(cdw[(t + 16 * mt) * 4 + 3]);
      }
      a1[mt] = a;
    }

    // --- C-init: acc = staged sum + bSum ---
    f32x4 acc[2][4];
#pragma unroll
    for (int mt = 0; mt < 2; ++mt)
#pragma unroll
      for (int nt = 0; nt < 4; ++nt)
#pragma unroll
        for (int j = 0; j < 4; ++j) {
          const int row = g * 4 + j + 16 * mt, col = t + 16 * nt;
          acc[mt][nt][j] = bf2f(xw[row * 72 + col]) + bS_r[nt];
        }
    // --- layer-1 MFMA (ea + radial), K=32 ---
#pragma unroll
    for (int mt = 0; mt < 2; ++mt)
#pragma unroll
      for (int nt = 0; nt < 4; ++nt) {
        const short8 b = *reinterpret_cast<const short8*>(&S.Bea[(t + 16 * nt) * 40 + g * 8]);
        acc[mt][nt] = __builtin_amdgcn_mfma_f32_16x16x32_bf16(a1[mt], b, acc[mt][nt], 0, 0, 0);
      }
#pragma unroll
    for (int mt = 0; mt < 2; ++mt)
#pragma unroll
      for (int nt = 0; nt < 4; ++nt)
#pragma unroll
        for (int j = 0; j < 4; ++j) {
          const float v = fmaxf(acc[mt][nt][j], 0.f);
          xw[(g * 4 + j + 16 * mt) * 72 + t + 16 * nt] = f2bf(v);
        }
    // --- layer-2 MFMA: m = relu(t1 @ We2 + be2) ---
    short8 A2[2][2];
#pragma unroll
    for (int mt = 0; mt < 2; ++mt)
#pragma unroll
      for (int kt = 0; kt < 2; ++kt)
        A2[mt][kt] = *reinterpret_cast<const short8*>(&xw[(t + 16 * mt) * 72 + kt * 32 + g * 8]);
    f32x4 m2[2][4];
#pragma unroll
    for (int mt = 0; mt < 2; ++mt)
#pragma unroll
      for (int nt = 0; nt < 4; ++nt) {
        f32x4 c;
        c[0] = be2_r[nt]; c[1] = be2_r[nt]; c[2] = be2_r[nt]; c[3] = be2_r[nt];
#pragma unroll
        for (int kt = 0; kt < 2; ++kt) {
          const short8 b = *reinterpret_cast<const short8*>(
              &S.We2t[(t + 16 * nt) * 72 + kt * 32 + g * 8]);
          c = __builtin_amdgcn_mfma_f32_16x16x32_bf16(A2[mt][kt], b, c, 0, 0, 0);
        }
#pragma unroll
        for (int j = 0; j < 4; ++j) c[j] = fmaxf(c[j], 0.f);
        m2[mt][nt] = c;
      }
#pragma unroll
    for (int mt = 0; mt < 2; ++mt)
#pragma unroll
      for (int nt = 0; nt < 4; ++nt)
#pragma unroll
        for (int j = 0; j < 4; ++j)
          xw[(g * 4 + j + 16 * mt) * 72 + t + 16 * nt] = f2bf(m2[mt][nt][j]);

    // --- coord MLP MFMA: p = relu(m @ Wc1 + bc1) ---
    short8 A3[2][2];
#pragma unroll
    for (int mt = 0; mt < 2; ++mt)
#pragma unroll
      for (int kt = 0; kt < 2; ++kt)
        A3[mt][kt] = *reinterpret_cast<const short8*>(&xw[(t + 16 * mt) * 72 + kt * 32 + g * 8]);
    f32x4 p[2][4];
#pragma unroll
    for (int mt = 0; mt < 2; ++mt)
#pragma unroll
      for (int nt = 0; nt < 4; ++nt) {
        f32x4 c;
        c[0] = bc1_r[nt]; c[1] = bc1_r[nt]; c[2] = bc1_r[nt]; c[3] = bc1_r[nt];
#pragma unroll
        for (int kt = 0; kt < 2; ++kt) {
          const short8 b = *reinterpret_cast<const short8*>(
              &S.Wc1t[(t + 16 * nt) * 72 + kt * 32 + g * 8]);
          c = __builtin_amdgcn_mfma_f32_16x16x32_bf16(A3[mt][kt], b, c, 0, 0, 0);
        }
#pragma unroll
        for (int j = 0; j < 4; ++j) c[j] = fmaxf(c[j], 0.f);
        p[mt][nt] = c;
      }
    // --- s = p . Wc2 + bc2 ---
    float sv[2][4];
#pragma unroll
    for (int mt = 0; mt < 2; ++mt)
#pragma unroll
      for (int j = 0; j < 4; ++j) {
        float ps = 0.f;
#pragma unroll
        for (int nt = 0; nt < 4; ++nt) ps = fmaf(p[mt][nt][j], wc2_r[nt], ps);
        sv[mt][j] = ps;
      }
#pragma unroll
    for (int d = 1; d < 16; d <<= 1)
#pragma unroll
      for (int mt = 0; mt < 2; ++mt)
#pragma unroll
        for (int j = 0; j < 4; ++j) sv[mt][j] += __shfl_xor(sv[mt][j], d, 64);
#pragma unroll
    for (int mt = 0; mt < 2; ++mt)
#pragma unroll
      for (int j = 0; j < 4; ++j) sv[mt][j] += bc2v;

    // --- store s per row (overwrites radial slot; radial already consumed) ---
#pragma unroll
    for (int mt = 0; mt < 2; ++mt)
#pragma unroll
      for (int j = 0; j < 4; ++j)
        if (t == 0) cdw[(g * 4 + j + 16 * mt) * 4 + 3] = sv[mt][j];

    // --- run-compressed agg_m: lane owns column `lane`, scan 32 sorted rows
    {
      float accm = 0.f;
#pragma unroll
      for (int r = 0; r < 32; ++r) {
        const int rIr = idxw[r];
        const bool valid = (e0 + r) < E;
        if (valid) accm += bf2f(xw[r * 72 + lane]);
        const bool closes = (r == 31) || ((e0 + r + 1) >= E) || (idxw[r + 1] != rIr);
        if (valid && closes) {
          atomAddF(&agg_m[(size_t)rIr * 64 + lane], accm);
          accm = 0.f;
        }
      }
    }
    // --- run-compressed agg_x: lanes 0..2 (components) ---
    if (lane < 3) {
      float accx = 0.f;
#pragma unroll
      for (int r = 0; r < 32; ++r) {
        const int rIr = idxw[r];
        const bool valid = (e0 + r) < E;
        if (valid) accx += cdw[r * 4 + lane] * cdw[r * 4 + 3];
        const bool closes = (r == 31) || ((e0 + r + 1) >= E) || (idxw[r + 1] != rIr);
        if (valid && closes) {
          atomAddF(&agg_x[(size_t)rIr * 3 + lane], accx);
          accx = 0.f;
        }
      }
    }
  }
}

// ---------------- k_node ----------------
__global__ __launch_bounds__(256) void k_node(
    const float* __restrict__ h, const float* __restrict__ agg_m,
    const float* __restrict__ agg_x, const int* __restrict__ deg,
    const float* __restrict__ co,
    const float* __restrict__ Wn1, const float* __restrict__ bn1,
    const float* __restrict__ Wn2, const float* __restrict__ bn2,
    const float* __restrict__ Wo, const float* __restrict__ bo,
    float* __restrict__ out, float* __restrict__ co_out, int N) {
  __shared__ float Wn1s[128 * 64];
  __shared__ float Wn2s[64 * 64];
  __shared__ float Wos[64 * 64];
  __shared__ float bn1s[64], bn2s[64], bos[64];
  __shared__ float xls[4][136];

  for (int i = threadIdx.x; i < 128 * 64; i += 256) Wn1s[i] = Wn1[i];
  for (int i = threadIdx.x; i < 64 * 64; i += 256) {
    Wn2s[i] = Wn2[i];
    Wos[i] = Wo[i];
  }
  if (threadIdx.x < 64) {
    bn1s[threadIdx.x] = bn1[threadIdx.x];
    bn2s[threadIdx.x] = bn2[threadIdx.x];
    bos[threadIdx.x] = bo[threadIdx.x];
  }
  __syncthreads();

  const int wave = threadIdx.x >> 6, lane = threadIdx.x & 63;
  float* xw = xls[wave];
  const int nwaves = gridDim.x * 4;

  for (int n = blockIdx.x * 4 + wave; n < N; n += nwaves) {
    xw[lane] = h[(size_t)n * 64 + lane];
    xw[64 + lane] = agg_m[(size_t)n * 64 + lane];

    float a = bn1s[lane];
    for (int kk = 0; kk < 32; ++kk) {
      const float4 xv = *reinterpret_cast<const float4*>(&xw[kk * 4]);
      a = fmaf(xv.x, Wn1s[(kk * 4 + 0) * 64 + lane], a);
      a = fmaf(xv.y, Wn1s[(kk * 4 + 1) * 64 + lane], a);
      a = fmaf(xv.z, Wn1s[(kk * 4 + 2) * 64 + lane], a);
      a = fmaf(xv.w, Wn1s[(kk * 4 + 3) * 64 + lane], a);
    }
    a = fmaxf(a, 0.0f);
    xw[lane] = a;

    float a2 = bn2s[lane];
    for (int kk = 0; kk < 16; ++kk) {
      const float4 xv = *reinterpret_cast<const float4*>(&xw[kk * 4]);
      a2 = fmaf(xv.x, Wn2s[(kk * 4 + 0) * 64 + lane], a2);
      a2 = fmaf(xv.y, Wn2s[(kk * 4 + 1) * 64 + lane], a2);
      a2 = fmaf(xv.z, Wn2s[(kk * 4 + 2) * 64 + lane], a2);
      a2 = fmaf(xv.w, Wn2s[(kk * 4 + 3) * 64 + lane], a2);
    }
    xw[64 + lane] = a2;

    float a3 = bos[lane];
    for (int kk = 0; kk < 16; ++kk) {
      const float4 xv = *reinterpret_cast<const float4*>(&xw[64 + kk * 4]);
      a3 = fmaf(xv.x, Wos[(kk * 4 + 0) * 64 + lane], a3);
      a3 = fmaf(xv.y, Wos[(kk * 4 + 1) * 64 + lane], a3);
      a3 = fmaf(xv.z, Wos[(kk * 4 + 2) * 64 + lane], a3);
      a3 = fmaf(xv.w, Wos[(kk * 4 + 3) * 64 + lane], a3);
    }
    out[(size_t)n * 64 + lane] = a3;

    if (lane < 3)
      co_out[(size_t)n * 3 + lane] =
          co[(size_t)n * 3 + lane] +
          agg_x[(size_t)n * 3 + lane] / fmaxf((float)deg[n], 1.0f);
  }
}

extern "C" void kernel_launch(void* const* d_in, const int* in_sizes, int n_in,
                              void* d_out, int out_size, void* d_ws, size_t ws_size,
                              hipStream_t stream) {
  const float* nf = (const float*)d_in[0];
  const float* ea = (const float*)d_in[1];
  const float* co = (const float*)d_in[2];
  const int* ei = (const int*)d_in[3];
  const float* W_in = (const float*)d_in[4];
  const float* b_in = (const float*)d_in[5];
  const float* W_out = (const float*)d_in[6];
  const float* b_out = (const float*)d_in[7];
  const float* We1 = (const float*)d_in[8];
  const float* be1 = (const float*)d_in[9];
  const float* We2 = (const float*)d_in[10];
  const float* be2 = (const float*)d_in[11];
  const float* Wn1 = (const float*)d_in[12];
  const float* bn1 = (const float*)d_in[13];
  const float* Wn2 = (const float*)d_in[14];
  const float* bn2 = (const float*)d_in[15];
  const float* Wc1 = (const float*)d_in[16];
  const float* bc1 = (const float*)d_in[17];
  const float* Wc2 = (const float*)d_in[18];
  const float* bc2 = (const float*)d_in[19];

  const int N = in_sizes[0] / 32;
  const int E = in_sizes[1] / 16;

  float* ws = (float*)d_ws;
  float* h = ws;
  float* agg_m = ws + (size_t)N * 64;
  float* agg_x = agg_m + (size_t)N * 64;
  int* deg = (int*)(agg_x + (size_t)N * 3);
  float* WA = (float*)(deg + N);
  float* WB = WA + 2048;
  float* bSum = WB + 2048;
  int* rowStart = (int*)(bSum + 64);
  int* rowNext = rowStart + N;
  int* perm = rowNext + N;
  int* rowS = perm + E;
  int* colS = rowS + E;
  int* bsumBuf = colS + E;

  float* outp = (float*)d_out;
  float* co_out = outp + (size_t)N * 64;
  unsigned short* gA = (unsigned short*)d_out;
  unsigned short* gB = gA + (size_t)N * 64;

  const int nb = (N + 255) / 256;

  k_fold<<<1, 256, 0, stream>>>(W_in, b_in, We1, be1, WA, WB, bSum);
  k_embed<<<2048, 256, 0, stream>>>(nf, W_in, b_in, WA, WB, h, gA, gB, agg_m, N);
  k_hist<<<512, 256, 0, stream>>>(ei, deg, E);
  k_scanA<<<nb, 256, 0, stream>>>(deg, rowStart, bsumBuf, N);
  k_scanB<<<1, 512, 0, stream>>>(bsumBuf, nb);
  k_scanC<<<nb, 256, 0, stream>>>(rowStart, bsumBuf, rowNext, N);
  k_scatter<<<512, 256, 0, stream>>>(ei, rowNext, perm, rowS, colS, E);
  k_edge<<<768, 256, 0, stream>>>(gA, gB, ea, co, perm, rowS, colS, We1, bSum,
                                  be2, We2, bc1, Wc1, Wc2, bc2, agg_m, agg_x, E);
  k_node<<<2048, 256, 0, stream>>>(h, agg_m, agg_x, deg, co, Wn1, bn1, Wn2,
                                   bn2, W_out, b_out, outp, co_out, N);
}